// Round 14
// baseline (85.754 us; speedup 1.0000x reference)
//
#include <hip/hip_runtime.h>

// Bidirectional NN-MSE via MFMA — R14: QT=4 (four query fragments per wave).
// Each 2 KB A-tile-pair feeds 8 MFMAs -> 256 B of L2 A-stream per MFMA.
// L2-intensity lever confirmed bidirectionally: R12 (1 KB/MFMA) +6 us,
// R13 (512 B/MFMA) -3.4 us. Register audit: 64 pinned acc + 32 clobbers +
// 40 misc ~ 146 VGPR, no spill at 256-thr blocks without launch_bounds cap.
//
//   loss = w * mean_n min_j ||p_n - g_j||^2 + (1-w) * mean_m min_i ||g_m - p_i||^2
//
// d^2 = qq - 2 q.r + rr inside mfma_f32_32x32x16_bf16 (K=16), 2-term bf16
// split per operand (exact bf16xbf16 products; absmax 0 R2-R13).

#define NPTS   16384
#define QT     4
#define QBLK   512                // 4 waves x 4 tiles x 32 queries
#define QCH    (NPTS / QBLK)      // 32 query chunks
#define SSPLIT 8                  // ref splits
#define RBLK   (NPTS / SSPLIT)    // 2048 refs streamed per block (64 tiles)
#define NB1    (2 * QCH * SSPLIT) // 512 blocks

typedef __attribute__((ext_vector_type(8)))  __bf16 bf16x8;
typedef __attribute__((ext_vector_type(16))) float  floatx16;

union frag16 { __bf16 v[16]; uint4 q[2]; };

// One thread per (role, point): builds A-form (ref) and B-form (query)
// fragments. A-form pre-swizzled in MFMA wave order: uint4 index
// (p>>5)*64 + half*32 + (p&31) -> each wave tile read is one contiguous,
// perfectly-coalesced 1 KB global_load_dwordx4 burst.
__global__ __launch_bounds__(256) void prep_kernel(
    const float* __restrict__ pred, const float* __restrict__ gt,
    uint4* __restrict__ aform, uint4* __restrict__ bform,
    float* __restrict__ out)
{
    const int i = blockIdx.x * 256 + threadIdx.x;   // 0 .. 2*NPTS-1
    if (i == 0) out[0] = 0.0f;
    const int role = (i < NPTS) ? 0 : 1;            // 0=pred, 1=gt
    const int p = i - role * NPTS;
    const float* __restrict__ src = role ? gt : pred;

    const float x = src[p * 3 + 0], y = src[p * 3 + 1], z = src[p * 3 + 2];
    const float nn = x * x + y * y + z * z;
    const __bf16 xh = (__bf16)x, yh = (__bf16)y, zh = (__bf16)z;
    const __bf16 xl = (__bf16)(x - (float)xh);
    const __bf16 yl = (__bf16)(y - (float)yh);
    const __bf16 zl = (__bf16)(z - (float)zh);
    const __bf16 nh = (__bf16)nn;
    const __bf16 nl = (__bf16)(nn - (float)nh);
    const __bf16 one = (__bf16)1.0f;

    frag16 A;
    A.v[0]  = (__bf16)(-2.0f * (float)xh); A.v[1]  = A.v[0];
    A.v[2]  = (__bf16)(-2.0f * (float)xl); A.v[3]  = A.v[2];
    A.v[4]  = (__bf16)(-2.0f * (float)yh); A.v[5]  = A.v[4];
    A.v[6]  = (__bf16)(-2.0f * (float)yl); A.v[7]  = A.v[6];
    A.v[8]  = (__bf16)(-2.0f * (float)zh); A.v[9]  = A.v[8];
    A.v[10] = (__bf16)(-2.0f * (float)zl); A.v[11] = A.v[10];
    A.v[12] = nh;  A.v[13] = nl;  A.v[14] = one;  A.v[15] = one;

    frag16 B;
    B.v[0] = xh;  B.v[1]  = xl;  B.v[2]  = xh;  B.v[3]  = xl;
    B.v[4] = yh;  B.v[5]  = yl;  B.v[6]  = yh;  B.v[7]  = yl;
    B.v[8] = zh;  B.v[9]  = zl;  B.v[10] = zh;  B.v[11] = zl;
    B.v[12] = one; B.v[13] = one; B.v[14] = nh;  B.v[15] = nl;

    uint4* da = aform + (size_t)role * (NPTS * 2)
              + ((p >> 5) * 64 + (p & 31));
    da[0]  = A.q[0];        // half 0 (k=0..7)  at +0
    da[32] = A.q[1];        // half 1 (k=8..15) at +32
    uint4* db = bform + (size_t)role * (NPTS * 2) + p * 2;
    db[0] = B.q[0];
    db[1] = B.q[1];
}

// R11's proven asm block: 2 MFMA into fixed dest banks + 16 v_min3 into
// "+v"-pinned accumulators. Emitted once per query-fragment per tile-pair.
#define MFMA_MIN_BLOCK(BQ, M)                                               \
    asm volatile(                                                           \
        "v_mfma_f32_32x32x16_bf16 v[32:47], %[A0], %[B], %[Z]\n\t"          \
        "v_mfma_f32_32x32x16_bf16 v[48:63], %[A1], %[B], %[Z]\n\t"          \
        "s_nop 7\n\ts_nop 7\n\ts_nop 7\n\ts_nop 7\n\t"                      \
        "v_min3_f32 %[M0],  %[M0],  v32, v48\n\t"                           \
        "v_min3_f32 %[M1],  %[M1],  v33, v49\n\t"                           \
        "v_min3_f32 %[M2],  %[M2],  v34, v50\n\t"                           \
        "v_min3_f32 %[M3],  %[M3],  v35, v51\n\t"                           \
        "v_min3_f32 %[M4],  %[M4],  v36, v52\n\t"                           \
        "v_min3_f32 %[M5],  %[M5],  v37, v53\n\t"                           \
        "v_min3_f32 %[M6],  %[M6],  v38, v54\n\t"                           \
        "v_min3_f32 %[M7],  %[M7],  v39, v55\n\t"                           \
        "v_min3_f32 %[M8],  %[M8],  v40, v56\n\t"                           \
        "v_min3_f32 %[M9],  %[M9],  v41, v57\n\t"                           \
        "v_min3_f32 %[M10], %[M10], v42, v58\n\t"                           \
        "v_min3_f32 %[M11], %[M11], v43, v59\n\t"                           \
        "v_min3_f32 %[M12], %[M12], v44, v60\n\t"                           \
        "v_min3_f32 %[M13], %[M13], v45, v61\n\t"                           \
        "v_min3_f32 %[M14], %[M14], v46, v62\n\t"                           \
        "v_min3_f32 %[M15], %[M15], v47, v63"                               \
        : [M0] "+v"(M[0]),  [M1] "+v"(M[1]),  [M2] "+v"(M[2]),              \
          [M3] "+v"(M[3]),  [M4] "+v"(M[4]),  [M5] "+v"(M[5]),              \
          [M6] "+v"(M[6]),  [M7] "+v"(M[7]),  [M8] "+v"(M[8]),              \
          [M9] "+v"(M[9]),  [M10] "+v"(M[10]), [M11] "+v"(M[11]),           \
          [M12] "+v"(M[12]), [M13] "+v"(M[13]), [M14] "+v"(M[14]),          \
          [M15] "+v"(M[15])                                                 \
        : [A0] "v"(a0), [A1] "v"(a1), [B] "v"(BQ), [Z] "v"(zero)            \
        : "v32", "v33", "v34", "v35", "v36", "v37", "v38", "v39",           \
          "v40", "v41", "v42", "v43", "v44", "v45", "v46", "v47",           \
          "v48", "v49", "v50", "v51", "v52", "v53", "v54", "v55",           \
          "v56", "v57", "v58", "v59", "v60", "v61", "v62", "v63")

#define TREE_STORE(M, OFS)                                                  \
    {                                                                       \
        float a = fminf(fminf(M[0], M[1]), fminf(M[2], M[3]));              \
        float b = fminf(fminf(M[4], M[5]), fminf(M[6], M[7]));              \
        float c = fminf(fminf(M[8], M[9]), fminf(M[10], M[11]));            \
        float d = fminf(fminf(M[12], M[13]), fminf(M[14], M[15]));          \
        float v = fminf(fminf(a, b), fminf(c, d));                          \
        v = fminf(v, __shfl_xor(v, 32));                                    \
        if (half == 0) pout[(OFS) + lid] = v;                               \
    }

__global__ __launch_bounds__(256) void nn_part_kernel(
    const uint4* __restrict__ aform, const uint4* __restrict__ bform,
    float* __restrict__ partial)
{
    const int bx   = blockIdx.x;           // 0..NB1-1
    const int dir  = bx >> 8;              // 0: Q=pred,R=gt ; 1: Q=gt,R=pred
    const int qc   = (bx & 255) >> 3;      // 0..31
    const int s    = bx & 7;               // 0..7
    const int tid  = threadIdx.x;
    const int lane = tid & 63;
    const int wave = tid >> 6;
    const int lid  = lane & 31;
    const int half = lane >> 5;

    // dir 0: queries=pred(role 0), refs=gt(role 1); dir 1 swapped
    const uint4* __restrict__ Aref = aform + (size_t)(dir ? 0 : 1) * (NPTS * 2);
    const uint4* __restrict__ Bqry = bform + (size_t)(dir ? 1 : 0) * (NPTS * 2);

    // ---- four query B-fragments per wave (prebuilt, 16 B/lane) ----
    const int qbase = qc * QBLK + wave * (QT * 32);
    const bf16x8 bq0 = __builtin_bit_cast(bf16x8, Bqry[(qbase + lid) * 2 + half]);
    const bf16x8 bq1 = __builtin_bit_cast(bf16x8, Bqry[(qbase + 32 + lid) * 2 + half]);
    const bf16x8 bq2 = __builtin_bit_cast(bf16x8, Bqry[(qbase + 64 + lid) * 2 + half]);
    const bf16x8 bq3 = __builtin_bit_cast(bf16x8, Bqry[(qbase + 96 + lid) * 2 + half]);

    floatx16 zero;
#pragma unroll
    for (int k = 0; k < 16; ++k) zero[k] = 0.0f;

    float ma[16], mb[16], mc[16], md[16];
#pragma unroll
    for (int k = 0; k < 16; ++k) {
        ma[k] = 3.4e38f; mb[k] = 3.4e38f; mc[k] = 3.4e38f; md[k] = 3.4e38f;
    }

    // ---- hot loop: 2 KB A-stream feeds 8 MFMAs (256 B/MFMA) ----
    const uint4* gp = Aref + (size_t)s * (RBLK * 2) + half * 32 + lid;
    for (int t = 0; t < RBLK / 32; t += 2) {
        const bf16x8 a0 = __builtin_bit_cast(bf16x8, gp[t * 64]);
        const bf16x8 a1 = __builtin_bit_cast(bf16x8, gp[t * 64 + 64]);
        MFMA_MIN_BLOCK(bq0, ma);
        MFMA_MIN_BLOCK(bq1, mb);
        MFMA_MIN_BLOCK(bq2, mc);
        MFMA_MIN_BLOCK(bq3, md);
    }

    // ---- tail: in-lane trees + one shuffle each, plain coalesced store ----
    float* pout = partial + ((size_t)((dir * QCH + qc) * SSPLIT + s)) * QBLK
                + wave * (QT * 32);
    TREE_STORE(ma, 0)
    TREE_STORE(mb, 32)
    TREE_STORE(mc, 64)
    TREE_STORE(md, 96)
}

// Combine: min over the SSPLIT ref-splits per query, weighted sum into out.
__global__ __launch_bounds__(256) void nn_combine_kernel(
    const float* __restrict__ partial, const float* __restrict__ weight,
    float* __restrict__ out)
{
    const int b   = blockIdx.x;        // 0..127 : dir = b>>6
    const int dir = b >> 6;
    const int g   = (b & 63) * 256 + threadIdx.x;   // global query index
    const int qc  = g >> 9;            // /QBLK
    const int j   = g & 511;           // %QBLK
    const int t   = threadIdx.x;

    const float* p = partial + ((size_t)((dir * QCH + qc) * SSPLIT)) * QBLK + j;
    float v = p[0];
#pragma unroll
    for (int s = 1; s < SSPLIT; ++s)
        v = fminf(v, p[s * QBLK]);

    for (int off = 32; off; off >>= 1) v += __shfl_down(v, off);
    __shared__ float ws[4];
    if ((t & 63) == 0) ws[t >> 6] = v;
    __syncthreads();
    if (t == 0) {
        const float sum = ws[0] + ws[1] + ws[2] + ws[3];
        const float wgt = weight[0];
        const float scale = (dir ? (1.0f - wgt) : wgt) / (3.0f * (float)NPTS);
        atomicAdd(out, sum * scale);
    }
}

extern "C" void kernel_launch(void* const* d_in, const int* in_sizes, int n_in,
                              void* d_out, int out_size, void* d_ws, size_t ws_size,
                              hipStream_t stream) {
    const float* pred   = (const float*)d_in[0];
    const float* gt     = (const float*)d_in[1];
    const float* weight = (const float*)d_in[2];

    // ws: [partial 1 MB][aform 1 MB][bform 1 MB]
    float* partial = (float*)d_ws;                       // 2*QCH*SSPLIT*QBLK f32
    uint4* aform = (uint4*)((char*)d_ws + (size_t)2 * QCH * SSPLIT * QBLK * 4);
    uint4* bform = aform + (size_t)2 * NPTS * 2;

    prep_kernel<<<2 * NPTS / 256, 256, 0, stream>>>(pred, gt, aform, bform,
                                                    (float*)d_out);
    nn_part_kernel<<<NB1, 256, 0, stream>>>(aform, bform, partial);
    nn_combine_kernel<<<2 * QCH * 2, 256, 0, stream>>>(partial, weight, (float*)d_out);
}

// Round 15
// 84.544 us; speedup vs baseline: 1.0143x; 1.0143x over previous
//
#include <hip/hip_runtime.h>

// Bidirectional NN-MSE via MFMA — R15: R13 (best, 81.6 us) with the two
// asm blocks merged into ONE interleaved block: 4 MFMAs issued back-to-back
// (issue burst covers the read hazard), 2 s_nop instead of 8, then 32 min3.
// Removes ~48 forced-idle cycles per iteration (~5 us chip-wide).
//
//   loss = w * mean_n min_j ||p_n - g_j||^2 + (1-w) * mean_m min_i ||g_m - p_i||^2
//
// d^2 = qq - 2 q.r + rr inside mfma_f32_32x32x16_bf16 (K=16), 2-term bf16
// split per operand (exact bf16xbf16 products; absmax 0 R2-R14).
// Register audit: 64 clobber + 32 pinned acc + 16 zero + 16 bq/a + ~12 addr
// ~ 140 VGPR -> ~3 waves/SIMD, no spill (R5 signature checked).

#define NPTS   16384
#define QBLK   256                // 4 waves x 2 tiles x 32 queries (QT=2)
#define QCH    (NPTS / QBLK)      // 64 query chunks
#define SSPLIT 8                  // ref splits
#define RBLK   (NPTS / SSPLIT)    // 2048 refs streamed per block (64 tiles)
#define NB1    (2 * QCH * SSPLIT) // 1024 blocks

typedef __attribute__((ext_vector_type(8)))  __bf16 bf16x8;
typedef __attribute__((ext_vector_type(16))) float  floatx16;

union frag16 { __bf16 v[16]; uint4 q[2]; };

// One thread per (role, point): builds A-form (ref) and B-form (query)
// fragments. A-form pre-swizzled in MFMA wave order: uint4 index
// (p>>5)*64 + half*32 + (p&31) -> each wave tile read is one contiguous,
// perfectly-coalesced 1 KB global_load_dwordx4 burst.
__global__ __launch_bounds__(256) void prep_kernel(
    const float* __restrict__ pred, const float* __restrict__ gt,
    uint4* __restrict__ aform, uint4* __restrict__ bform,
    float* __restrict__ out)
{
    const int i = blockIdx.x * 256 + threadIdx.x;   // 0 .. 2*NPTS-1
    if (i == 0) out[0] = 0.0f;
    const int role = (i < NPTS) ? 0 : 1;            // 0=pred, 1=gt
    const int p = i - role * NPTS;
    const float* __restrict__ src = role ? gt : pred;

    const float x = src[p * 3 + 0], y = src[p * 3 + 1], z = src[p * 3 + 2];
    const float nn = x * x + y * y + z * z;
    const __bf16 xh = (__bf16)x, yh = (__bf16)y, zh = (__bf16)z;
    const __bf16 xl = (__bf16)(x - (float)xh);
    const __bf16 yl = (__bf16)(y - (float)yh);
    const __bf16 zl = (__bf16)(z - (float)zh);
    const __bf16 nh = (__bf16)nn;
    const __bf16 nl = (__bf16)(nn - (float)nh);
    const __bf16 one = (__bf16)1.0f;

    frag16 A;
    A.v[0]  = (__bf16)(-2.0f * (float)xh); A.v[1]  = A.v[0];
    A.v[2]  = (__bf16)(-2.0f * (float)xl); A.v[3]  = A.v[2];
    A.v[4]  = (__bf16)(-2.0f * (float)yh); A.v[5]  = A.v[4];
    A.v[6]  = (__bf16)(-2.0f * (float)yl); A.v[7]  = A.v[6];
    A.v[8]  = (__bf16)(-2.0f * (float)zh); A.v[9]  = A.v[8];
    A.v[10] = (__bf16)(-2.0f * (float)zl); A.v[11] = A.v[10];
    A.v[12] = nh;  A.v[13] = nl;  A.v[14] = one;  A.v[15] = one;

    frag16 B;
    B.v[0] = xh;  B.v[1]  = xl;  B.v[2]  = xh;  B.v[3]  = xl;
    B.v[4] = yh;  B.v[5]  = yl;  B.v[6]  = yh;  B.v[7]  = yl;
    B.v[8] = zh;  B.v[9]  = zl;  B.v[10] = zh;  B.v[11] = zl;
    B.v[12] = one; B.v[13] = one; B.v[14] = nh;  B.v[15] = nl;

    uint4* da = aform + (size_t)role * (NPTS * 2)
              + ((p >> 5) * 64 + (p & 31));
    da[0]  = A.q[0];        // half 0 (k=0..7)  at +0
    da[32] = A.q[1];        // half 1 (k=8..15) at +32
    uint4* db = bform + (size_t)role * (NPTS * 2) + p * 2;
    db[0] = B.q[0];
    db[1] = B.q[1];
}

// Interleaved block: 4 MFMAs issued back-to-back (issue burst ~32 cyc covers
// most of the read hazard), 2 s_nop 7 for margin, then 32 v_min3 into
// "+v"-pinned accumulators. First 16 min3s read v[32:63] (oldest MFMAs,
// >=48 cyc old); second 16 read v[64:95] (>=64 cyc old by then).
#define MFMA4_MIN_BLOCK(BQ0, BQ1, MA, MB)                                   \
    asm volatile(                                                           \
        "v_mfma_f32_32x32x16_bf16 v[32:47], %[A0], %[B0], %[Z]\n\t"         \
        "v_mfma_f32_32x32x16_bf16 v[48:63], %[A1], %[B0], %[Z]\n\t"         \
        "v_mfma_f32_32x32x16_bf16 v[64:79], %[A0], %[B1], %[Z]\n\t"         \
        "v_mfma_f32_32x32x16_bf16 v[80:95], %[A1], %[B1], %[Z]\n\t"         \
        "s_nop 7\n\ts_nop 7\n\t"                                            \
        "v_min3_f32 %[MA0],  %[MA0],  v32, v48\n\t"                         \
        "v_min3_f32 %[MA1],  %[MA1],  v33, v49\n\t"                         \
        "v_min3_f32 %[MA2],  %[MA2],  v34, v50\n\t"                         \
        "v_min3_f32 %[MA3],  %[MA3],  v35, v51\n\t"                         \
        "v_min3_f32 %[MA4],  %[MA4],  v36, v52\n\t"                         \
        "v_min3_f32 %[MA5],  %[MA5],  v37, v53\n\t"                         \
        "v_min3_f32 %[MA6],  %[MA6],  v38, v54\n\t"                         \
        "v_min3_f32 %[MA7],  %[MA7],  v39, v55\n\t"                         \
        "v_min3_f32 %[MA8],  %[MA8],  v40, v56\n\t"                         \
        "v_min3_f32 %[MA9],  %[MA9],  v41, v57\n\t"                         \
        "v_min3_f32 %[MA10], %[MA10], v42, v58\n\t"                         \
        "v_min3_f32 %[MA11], %[MA11], v43, v59\n\t"                         \
        "v_min3_f32 %[MA12], %[MA12], v44, v60\n\t"                         \
        "v_min3_f32 %[MA13], %[MA13], v45, v61\n\t"                         \
        "v_min3_f32 %[MA14], %[MA14], v46, v62\n\t"                         \
        "v_min3_f32 %[MA15], %[MA15], v47, v63\n\t"                         \
        "v_min3_f32 %[MB0],  %[MB0],  v64, v80\n\t"                         \
        "v_min3_f32 %[MB1],  %[MB1],  v65, v81\n\t"                         \
        "v_min3_f32 %[MB2],  %[MB2],  v66, v82\n\t"                         \
        "v_min3_f32 %[MB3],  %[MB3],  v67, v83\n\t"                         \
        "v_min3_f32 %[MB4],  %[MB4],  v68, v84\n\t"                         \
        "v_min3_f32 %[MB5],  %[MB5],  v69, v85\n\t"                         \
        "v_min3_f32 %[MB6],  %[MB6],  v70, v86\n\t"                         \
        "v_min3_f32 %[MB7],  %[MB7],  v71, v87\n\t"                         \
        "v_min3_f32 %[MB8],  %[MB8],  v72, v88\n\t"                         \
        "v_min3_f32 %[MB9],  %[MB9],  v73, v89\n\t"                         \
        "v_min3_f32 %[MB10], %[MB10], v74, v90\n\t"                         \
        "v_min3_f32 %[MB11], %[MB11], v75, v91\n\t"                         \
        "v_min3_f32 %[MB12], %[MB12], v76, v92\n\t"                         \
        "v_min3_f32 %[MB13], %[MB13], v77, v93\n\t"                         \
        "v_min3_f32 %[MB14], %[MB14], v78, v94\n\t"                         \
        "v_min3_f32 %[MB15], %[MB15], v79, v95"                             \
        : [MA0] "+v"(MA[0]),  [MA1] "+v"(MA[1]),  [MA2] "+v"(MA[2]),        \
          [MA3] "+v"(MA[3]),  [MA4] "+v"(MA[4]),  [MA5] "+v"(MA[5]),        \
          [MA6] "+v"(MA[6]),  [MA7] "+v"(MA[7]),  [MA8] "+v"(MA[8]),        \
          [MA9] "+v"(MA[9]),  [MA10] "+v"(MA[10]), [MA11] "+v"(MA[11]),     \
          [MA12] "+v"(MA[12]), [MA13] "+v"(MA[13]), [MA14] "+v"(MA[14]),    \
          [MA15] "+v"(MA[15]),                                              \
          [MB0] "+v"(MB[0]),  [MB1] "+v"(MB[1]),  [MB2] "+v"(MB[2]),        \
          [MB3] "+v"(MB[3]),  [MB4] "+v"(MB[4]),  [MB5] "+v"(MB[5]),        \
          [MB6] "+v"(MB[6]),  [MB7] "+v"(MB[7]),  [MB8] "+v"(MB[8]),        \
          [MB9] "+v"(MB[9]),  [MB10] "+v"(MB[10]), [MB11] "+v"(MB[11]),     \
          [MB12] "+v"(MB[12]), [MB13] "+v"(MB[13]), [MB14] "+v"(MB[14]),    \
          [MB15] "+v"(MB[15])                                               \
        : [A0] "v"(a0), [A1] "v"(a1), [B0] "v"(BQ0), [B1] "v"(BQ1),         \
          [Z] "v"(zero)                                                     \
        : "v32", "v33", "v34", "v35", "v36", "v37", "v38", "v39",           \
          "v40", "v41", "v42", "v43", "v44", "v45", "v46", "v47",           \
          "v48", "v49", "v50", "v51", "v52", "v53", "v54", "v55",           \
          "v56", "v57", "v58", "v59", "v60", "v61", "v62", "v63",           \
          "v64", "v65", "v66", "v67", "v68", "v69", "v70", "v71",           \
          "v72", "v73", "v74", "v75", "v76", "v77", "v78", "v79",           \
          "v80", "v81", "v82", "v83", "v84", "v85", "v86", "v87",           \
          "v88", "v89", "v90", "v91", "v92", "v93", "v94", "v95")

__global__ __launch_bounds__(256) void nn_part_kernel(
    const uint4* __restrict__ aform, const uint4* __restrict__ bform,
    float* __restrict__ partial)
{
    const int bx   = blockIdx.x;           // 0..NB1-1
    const int dir  = bx >> 9;              // 0: Q=pred,R=gt ; 1: Q=gt,R=pred
    const int qc   = (bx & 511) >> 3;      // 0..63
    const int s    = bx & 7;               // 0..7
    const int tid  = threadIdx.x;
    const int lane = tid & 63;
    const int wave = tid >> 6;
    const int lid  = lane & 31;
    const int half = lane >> 5;

    // dir 0: queries=pred(role 0), refs=gt(role 1); dir 1 swapped
    const uint4* __restrict__ Aref = aform + (size_t)(dir ? 0 : 1) * (NPTS * 2);
    const uint4* __restrict__ Bqry = bform + (size_t)(dir ? 1 : 0) * (NPTS * 2);

    // ---- two query B-fragments per wave (prebuilt, 16 B/lane) ----
    const int qbase = qc * QBLK + wave * 64;
    const bf16x8 bq0 = __builtin_bit_cast(bf16x8, Bqry[(qbase + lid) * 2 + half]);
    const bf16x8 bq1 = __builtin_bit_cast(bf16x8, Bqry[(qbase + 32 + lid) * 2 + half]);

    floatx16 zero;
#pragma unroll
    for (int k = 0; k < 16; ++k) zero[k] = 0.0f;

    float ma[16], mb[16];
#pragma unroll
    for (int k = 0; k < 16; ++k) { ma[k] = 3.4e38f; mb[k] = 3.4e38f; }

    // ---- hot loop: 2 KB A-stream feeds 4 MFMAs (512 B/MFMA) ----
    const uint4* gp = Aref + (size_t)s * (RBLK * 2) + half * 32 + lid;
#pragma unroll 2
    for (int t = 0; t < RBLK / 32; t += 2) {
        const bf16x8 a0 = __builtin_bit_cast(bf16x8, gp[t * 64]);
        const bf16x8 a1 = __builtin_bit_cast(bf16x8, gp[t * 64 + 64]);
        MFMA4_MIN_BLOCK(bq0, bq1, ma, mb);
    }

    // ---- tail: in-lane trees + one shuffle each, plain coalesced store ----
    float* pout = partial + ((size_t)((dir * QCH + qc) * SSPLIT + s)) * QBLK
                + wave * 64;
    {
        float a = fminf(fminf(ma[0], ma[1]), fminf(ma[2], ma[3]));
        float b = fminf(fminf(ma[4], ma[5]), fminf(ma[6], ma[7]));
        float c = fminf(fminf(ma[8], ma[9]), fminf(ma[10], ma[11]));
        float d = fminf(fminf(ma[12], ma[13]), fminf(ma[14], ma[15]));
        float v = fminf(fminf(a, b), fminf(c, d));
        v = fminf(v, __shfl_xor(v, 32));
        if (half == 0) pout[lid] = v;
    }
    {
        float a = fminf(fminf(mb[0], mb[1]), fminf(mb[2], mb[3]));
        float b = fminf(fminf(mb[4], mb[5]), fminf(mb[6], mb[7]));
        float c = fminf(fminf(mb[8], mb[9]), fminf(mb[10], mb[11]));
        float d = fminf(fminf(mb[12], mb[13]), fminf(mb[14], mb[15]));
        float v = fminf(fminf(a, b), fminf(c, d));
        v = fminf(v, __shfl_xor(v, 32));
        if (half == 0) pout[32 + lid] = v;
    }
}

// Combine: min over the SSPLIT ref-splits per query, weighted sum into out.
__global__ __launch_bounds__(256) void nn_combine_kernel(
    const float* __restrict__ partial, const float* __restrict__ weight,
    float* __restrict__ out)
{
    const int b   = blockIdx.x;        // 0..127 : dir = b>>6, qc = b&63
    const int dir = b >> 6;
    const int qc  = b & 63;
    const int t   = threadIdx.x;

    const float* p = partial + ((size_t)((dir * QCH + qc) * SSPLIT)) * QBLK;
    float v = p[t];
#pragma unroll
    for (int s = 1; s < SSPLIT; ++s)
        v = fminf(v, p[s * QBLK + t]);

    for (int off = 32; off; off >>= 1) v += __shfl_down(v, off);
    __shared__ float ws[4];
    if ((t & 63) == 0) ws[t >> 6] = v;
    __syncthreads();
    if (t == 0) {
        const float sum = ws[0] + ws[1] + ws[2] + ws[3];
        const float wgt = weight[0];
        const float scale = (dir ? (1.0f - wgt) : wgt) / (3.0f * (float)NPTS);
        atomicAdd(out, sum * scale);
    }
}

extern "C" void kernel_launch(void* const* d_in, const int* in_sizes, int n_in,
                              void* d_out, int out_size, void* d_ws, size_t ws_size,
                              hipStream_t stream) {
    const float* pred   = (const float*)d_in[0];
    const float* gt     = (const float*)d_in[1];
    const float* weight = (const float*)d_in[2];

    // ws: [partial 1 MB][aform 1 MB][bform 1 MB]
    float* partial = (float*)d_ws;                       // 2*QCH*SSPLIT*QBLK f32
    uint4* aform = (uint4*)((char*)d_ws + (size_t)2 * QCH * SSPLIT * QBLK * 4);
    uint4* bform = aform + (size_t)2 * NPTS * 2;

    prep_kernel<<<2 * NPTS / 256, 256, 0, stream>>>(pred, gt, aform, bform,
                                                    (float*)d_out);
    nn_part_kernel<<<NB1, 256, 0, stream>>>(aform, bform, partial);
    nn_combine_kernel<<<2 * QCH, 256, 0, stream>>>(partial, weight, (float*)d_out);
}

// Round 16
// 81.023 us; speedup vs baseline: 1.0584x; 1.0435x over previous
//
#include <hip/hip_runtime.h>

// Bidirectional NN-MSE via MFMA — R16: REVERT to R13 (session best, 81.6 us).
// R14 (QT=4, 256 B/MFMA) regressed: L2 lever saturated, register pressure +
// low block count cost more than traffic saved. R15 (merged 4-MFMA asm block,
// 2 s_nop) regressed: nop cycles were already wave-overlapped; +32 clobbers
// hurt scheduling. R13's configuration is the empirical optimum.
//
//   loss = w * mean_n min_j ||p_n - g_j||^2 + (1-w) * mean_m min_i ||g_m - p_i||^2
//
// d^2 = qq - 2 q.r + rr inside mfma_f32_32x32x16_bf16 (K=16), 2-term bf16
// split per operand (exact bf16xbf16 products; absmax 0 R2-R15).
// Refs = A (rows), queries = B (cols); elementwise v_min3 accumulation in
// asm-pinned VGPRs (8 min3/MFMA = provable min-op floor), per-wave tree +
// single shuffle tail, plain coalesced partial stores, tiny combine kernel.

#define NPTS   16384
#define QBLK   256                // 4 waves x 2 tiles x 32 queries (QT=2)
#define QCH    (NPTS / QBLK)      // 64 query chunks
#define SSPLIT 8                  // ref splits
#define RBLK   (NPTS / SSPLIT)    // 2048 refs streamed per block (64 tiles)
#define NB1    (2 * QCH * SSPLIT) // 1024 blocks

typedef __attribute__((ext_vector_type(8)))  __bf16 bf16x8;
typedef __attribute__((ext_vector_type(16))) float  floatx16;

union frag16 { __bf16 v[16]; uint4 q[2]; };

// One thread per (role, point): builds A-form (ref) and B-form (query)
// fragments. A-form pre-swizzled in MFMA wave order: uint4 index
// (p>>5)*64 + half*32 + (p&31) -> each wave tile read is one contiguous,
// perfectly-coalesced 1 KB global_load_dwordx4 burst.
__global__ __launch_bounds__(256) void prep_kernel(
    const float* __restrict__ pred, const float* __restrict__ gt,
    uint4* __restrict__ aform, uint4* __restrict__ bform,
    float* __restrict__ out)
{
    const int i = blockIdx.x * 256 + threadIdx.x;   // 0 .. 2*NPTS-1
    if (i == 0) out[0] = 0.0f;
    const int role = (i < NPTS) ? 0 : 1;            // 0=pred, 1=gt
    const int p = i - role * NPTS;
    const float* __restrict__ src = role ? gt : pred;

    const float x = src[p * 3 + 0], y = src[p * 3 + 1], z = src[p * 3 + 2];
    const float nn = x * x + y * y + z * z;
    const __bf16 xh = (__bf16)x, yh = (__bf16)y, zh = (__bf16)z;
    const __bf16 xl = (__bf16)(x - (float)xh);
    const __bf16 yl = (__bf16)(y - (float)yh);
    const __bf16 zl = (__bf16)(z - (float)zh);
    const __bf16 nh = (__bf16)nn;
    const __bf16 nl = (__bf16)(nn - (float)nh);
    const __bf16 one = (__bf16)1.0f;

    frag16 A;
    A.v[0]  = (__bf16)(-2.0f * (float)xh); A.v[1]  = A.v[0];
    A.v[2]  = (__bf16)(-2.0f * (float)xl); A.v[3]  = A.v[2];
    A.v[4]  = (__bf16)(-2.0f * (float)yh); A.v[5]  = A.v[4];
    A.v[6]  = (__bf16)(-2.0f * (float)yl); A.v[7]  = A.v[6];
    A.v[8]  = (__bf16)(-2.0f * (float)zh); A.v[9]  = A.v[8];
    A.v[10] = (__bf16)(-2.0f * (float)zl); A.v[11] = A.v[10];
    A.v[12] = nh;  A.v[13] = nl;  A.v[14] = one;  A.v[15] = one;

    frag16 B;
    B.v[0] = xh;  B.v[1]  = xl;  B.v[2]  = xh;  B.v[3]  = xl;
    B.v[4] = yh;  B.v[5]  = yl;  B.v[6]  = yh;  B.v[7]  = yl;
    B.v[8] = zh;  B.v[9]  = zl;  B.v[10] = zh;  B.v[11] = zl;
    B.v[12] = one; B.v[13] = one; B.v[14] = nh;  B.v[15] = nl;

    uint4* da = aform + (size_t)role * (NPTS * 2)
              + ((p >> 5) * 64 + (p & 31));
    da[0]  = A.q[0];        // half 0 (k=0..7)  at +0
    da[32] = A.q[1];        // half 1 (k=8..15) at +32
    uint4* db = bform + (size_t)role * (NPTS * 2) + p * 2;
    db[0] = B.q[0];
    db[1] = B.q[1];
}

// R11's proven asm block: 2 MFMA into fixed dest banks + 16 v_min3 into
// "+v"-pinned accumulators. Emitted once per query-fragment per tile-pair.
#define MFMA_MIN_BLOCK(BQ, M)                                               \
    asm volatile(                                                           \
        "v_mfma_f32_32x32x16_bf16 v[32:47], %[A0], %[B], %[Z]\n\t"          \
        "v_mfma_f32_32x32x16_bf16 v[48:63], %[A1], %[B], %[Z]\n\t"          \
        "s_nop 7\n\ts_nop 7\n\ts_nop 7\n\ts_nop 7\n\t"                      \
        "v_min3_f32 %[M0],  %[M0],  v32, v48\n\t"                           \
        "v_min3_f32 %[M1],  %[M1],  v33, v49\n\t"                           \
        "v_min3_f32 %[M2],  %[M2],  v34, v50\n\t"                           \
        "v_min3_f32 %[M3],  %[M3],  v35, v51\n\t"                           \
        "v_min3_f32 %[M4],  %[M4],  v36, v52\n\t"                           \
        "v_min3_f32 %[M5],  %[M5],  v37, v53\n\t"                           \
        "v_min3_f32 %[M6],  %[M6],  v38, v54\n\t"                           \
        "v_min3_f32 %[M7],  %[M7],  v39, v55\n\t"                           \
        "v_min3_f32 %[M8],  %[M8],  v40, v56\n\t"                           \
        "v_min3_f32 %[M9],  %[M9],  v41, v57\n\t"                           \
        "v_min3_f32 %[M10], %[M10], v42, v58\n\t"                           \
        "v_min3_f32 %[M11], %[M11], v43, v59\n\t"                           \
        "v_min3_f32 %[M12], %[M12], v44, v60\n\t"                           \
        "v_min3_f32 %[M13], %[M13], v45, v61\n\t"                           \
        "v_min3_f32 %[M14], %[M14], v46, v62\n\t"                           \
        "v_min3_f32 %[M15], %[M15], v47, v63"                               \
        : [M0] "+v"(M[0]),  [M1] "+v"(M[1]),  [M2] "+v"(M[2]),              \
          [M3] "+v"(M[3]),  [M4] "+v"(M[4]),  [M5] "+v"(M[5]),              \
          [M6] "+v"(M[6]),  [M7] "+v"(M[7]),  [M8] "+v"(M[8]),              \
          [M9] "+v"(M[9]),  [M10] "+v"(M[10]), [M11] "+v"(M[11]),           \
          [M12] "+v"(M[12]), [M13] "+v"(M[13]), [M14] "+v"(M[14]),          \
          [M15] "+v"(M[15])                                                 \
        : [A0] "v"(a0), [A1] "v"(a1), [B] "v"(BQ), [Z] "v"(zero)            \
        : "v32", "v33", "v34", "v35", "v36", "v37", "v38", "v39",           \
          "v40", "v41", "v42", "v43", "v44", "v45", "v46", "v47",           \
          "v48", "v49", "v50", "v51", "v52", "v53", "v54", "v55",           \
          "v56", "v57", "v58", "v59", "v60", "v61", "v62", "v63")

__global__ __launch_bounds__(256) void nn_part_kernel(
    const uint4* __restrict__ aform, const uint4* __restrict__ bform,
    float* __restrict__ partial)
{
    const int bx   = blockIdx.x;           // 0..NB1-1
    const int dir  = bx >> 9;              // 0: Q=pred,R=gt ; 1: Q=gt,R=pred
    const int qc   = (bx & 511) >> 3;      // 0..63
    const int s    = bx & 7;               // 0..7
    const int tid  = threadIdx.x;
    const int lane = tid & 63;
    const int wave = tid >> 6;
    const int lid  = lane & 31;
    const int half = lane >> 5;

    // dir 0: queries=pred(role 0), refs=gt(role 1); dir 1 swapped
    const uint4* __restrict__ Aref = aform + (size_t)(dir ? 0 : 1) * (NPTS * 2);
    const uint4* __restrict__ Bqry = bform + (size_t)(dir ? 1 : 0) * (NPTS * 2);

    // ---- two query B-fragments per wave (prebuilt, 16 B/lane) ----
    const int qbase = qc * QBLK + wave * 64;
    const bf16x8 bq0 = __builtin_bit_cast(bf16x8, Bqry[(qbase + lid) * 2 + half]);
    const bf16x8 bq1 = __builtin_bit_cast(bf16x8, Bqry[(qbase + 32 + lid) * 2 + half]);

    floatx16 zero;
#pragma unroll
    for (int k = 0; k < 16; ++k) zero[k] = 0.0f;

    float ma[16], mb[16];
#pragma unroll
    for (int k = 0; k < 16; ++k) { ma[k] = 3.4e38f; mb[k] = 3.4e38f; }

    // ---- hot loop: 2 KB A-stream feeds 4 MFMAs (512 B/MFMA) ----
    const uint4* gp = Aref + (size_t)s * (RBLK * 2) + half * 32 + lid;
#pragma unroll 2
    for (int t = 0; t < RBLK / 32; t += 2) {
        const bf16x8 a0 = __builtin_bit_cast(bf16x8, gp[t * 64]);
        const bf16x8 a1 = __builtin_bit_cast(bf16x8, gp[t * 64 + 64]);
        MFMA_MIN_BLOCK(bq0, ma);
        MFMA_MIN_BLOCK(bq1, mb);
    }

    // ---- tail: in-lane trees + one shuffle each, plain coalesced store ----
    float* pout = partial + ((size_t)((dir * QCH + qc) * SSPLIT + s)) * QBLK
                + wave * 64;
    {
        float a = fminf(fminf(ma[0], ma[1]), fminf(ma[2], ma[3]));
        float b = fminf(fminf(ma[4], ma[5]), fminf(ma[6], ma[7]));
        float c = fminf(fminf(ma[8], ma[9]), fminf(ma[10], ma[11]));
        float d = fminf(fminf(ma[12], ma[13]), fminf(ma[14], ma[15]));
        float v = fminf(fminf(a, b), fminf(c, d));
        v = fminf(v, __shfl_xor(v, 32));
        if (half == 0) pout[lid] = v;
    }
    {
        float a = fminf(fminf(mb[0], mb[1]), fminf(mb[2], mb[3]));
        float b = fminf(fminf(mb[4], mb[5]), fminf(mb[6], mb[7]));
        float c = fminf(fminf(mb[8], mb[9]), fminf(mb[10], mb[11]));
        float d = fminf(fminf(mb[12], mb[13]), fminf(mb[14], mb[15]));
        float v = fminf(fminf(a, b), fminf(c, d));
        v = fminf(v, __shfl_xor(v, 32));
        if (half == 0) pout[32 + lid] = v;
    }
}

// Combine: min over the SSPLIT ref-splits per query, weighted sum into out.
__global__ __launch_bounds__(256) void nn_combine_kernel(
    const float* __restrict__ partial, const float* __restrict__ weight,
    float* __restrict__ out)
{
    const int b   = blockIdx.x;        // 0..127 : dir = b>>6, qc = b&63
    const int dir = b >> 6;
    const int qc  = b & 63;
    const int t   = threadIdx.x;

    const float* p = partial + ((size_t)((dir * QCH + qc) * SSPLIT)) * QBLK;
    float v = p[t];
#pragma unroll
    for (int s = 1; s < SSPLIT; ++s)
        v = fminf(v, p[s * QBLK + t]);

    for (int off = 32; off; off >>= 1) v += __shfl_down(v, off);
    __shared__ float ws[4];
    if ((t & 63) == 0) ws[t >> 6] = v;
    __syncthreads();
    if (t == 0) {
        const float sum = ws[0] + ws[1] + ws[2] + ws[3];
        const float wgt = weight[0];
        const float scale = (dir ? (1.0f - wgt) : wgt) / (3.0f * (float)NPTS);
        atomicAdd(out, sum * scale);
    }
}

extern "C" void kernel_launch(void* const* d_in, const int* in_sizes, int n_in,
                              void* d_out, int out_size, void* d_ws, size_t ws_size,
                              hipStream_t stream) {
    const float* pred   = (const float*)d_in[0];
    const float* gt     = (const float*)d_in[1];
    const float* weight = (const float*)d_in[2];

    // ws: [partial 512 KB][aform 1 MB][bform 1 MB]
    float* partial = (float*)d_ws;                       // 2*QCH*SSPLIT*QBLK f32
    uint4* aform = (uint4*)((char*)d_ws + (size_t)2 * QCH * SSPLIT * QBLK * 4);
    uint4* bform = aform + (size_t)2 * NPTS * 2;

    prep_kernel<<<2 * NPTS / 256, 256, 0, stream>>>(pred, gt, aform, bform,
                                                    (float*)d_out);
    nn_part_kernel<<<NB1, 256, 0, stream>>>(aform, bform, partial);
    nn_combine_kernel<<<2 * QCH, 256, 0, stream>>>(partial, weight, (float*)d_out);
}